// Round 4
// baseline (345.868 us; speedup 1.0000x reference)
//
#include <hip/hip_runtime.h>
#include <hip/hip_bf16.h>
#include <math.h>

// Problem constants
#define B_   8
#define H_   8
#define S_   2048
#define D_   64      // head dim
#define BH_  64      // B*H
#define DPROJ_ 512

typedef __attribute__((ext_vector_type(8))) short bf16x8;
typedef __attribute__((ext_vector_type(4))) float f32x4;

static __device__ __forceinline__ short f2bf(float f) {
    unsigned int x = __float_as_uint(f);
    x += 0x7fffu + ((x >> 16) & 1u);   // round-to-nearest-even
    return (short)(x >> 16);
}

// load 8 consecutive f32 and round to a bf16x8 fragment
static __device__ __forceinline__ bf16x8 load8_f32_bf16(const float* p) {
    const float4 a = ((const float4*)p)[0];
    const float4 b = ((const float4*)p)[1];
    bf16x8 r;
    r[0] = f2bf(a.x); r[1] = f2bf(a.y); r[2] = f2bf(a.z); r[3] = f2bf(a.w);
    r[4] = f2bf(b.x); r[5] = f2bf(b.y); r[6] = f2bf(b.z); r[7] = f2bf(b.w);
    return r;
}

// ---------------------------------------------------------------------------
// Kernel 1a: Q/K projection. 16 rows x 512 cols per block; C-tiles staged in
// LDS, then written out as coalesced dwordx4 (fixes 2B-store transaction bound).
//   q_ws,k_ws: [BH][S][64] bf16. q pre-scaled by 0.1125*log2(e).
// grid: (B*S/16, 2), block 256.
// ---------------------------------------------------------------------------
#define QKST 520   // LDS row stride (shorts): 1040B, 16B-aligned rows

__global__ __launch_bounds__(256)
void proj_qk_kernel(const float* __restrict__ query, const float* __restrict__ key,
                    const float* __restrict__ Wq, const float* __restrict__ bq,
                    const float* __restrict__ Wk, const float* __restrict__ bk,
                    short* __restrict__ qws, short* __restrict__ kws)
{
    __shared__ __align__(16) short tile[16 * QKST];

    const int tid  = threadIdx.x;
    const int wave = tid >> 6;
    const int lane = tid & 63;
    const int n    = lane & 15;
    const int quad = lane >> 4;
    const int r0   = blockIdx.x * 16;
    const int kind = blockIdx.y;             // 0=q, 1=k
    const int b    = r0 >> 11;
    const int s0   = r0 & 2047;
    const float QS = 0.1125f * 1.4426950408889634f;  // (0.9/8)*log2(e)

    const float* X    = kind ? key : query;
    const float* W    = kind ? Wk  : Wq;
    const float* bias = kind ? bk  : bq;
    short*       ows  = kind ? kws : qws;

    // A-frag: input rows (m = n), k = quad*8 + j
    bf16x8 af = load8_f32_bf16(X + (r0 + n) * 32 + quad * 8);
    #pragma unroll
    for (int i = 0; i < 8; ++i) {
        const int c0 = wave * 128 + i * 16;
        bf16x8 bfr = load8_f32_bf16(W + (c0 + n) * 32 + quad * 8);
        f32x4 acc = {0.f, 0.f, 0.f, 0.f};
        acc = __builtin_amdgcn_mfma_f32_16x16x32_bf16(af, bfr, acc, 0, 0, 0);
        const int c = c0 + n;                // C/D col = lane&15
        const float bsf = bias[c];
        #pragma unroll
        for (int r = 0; r < 4; ++r) {
            float v = acc[r] + bsf;
            if (kind == 0) v *= QS;
            tile[(quad * 4 + r) * QKST + c] = f2bf(v);   // row = quad*4+r
        }
    }
    __syncthreads();

    // write out: 128 chunks of (h,row), each 128B (8 lanes x 16B), coalesced
    #pragma unroll
    for (int k = 0; k < 4; ++k) {
        const int slot = k * 256 + tid;
        const int li   = slot & 7;
        const int chunk= slot >> 3;
        const int row  = chunk & 15;
        const int h    = chunk >> 4;
        uint4 vv = *(const uint4*)(tile + row * QKST + h * 64 + li * 8);
        *(uint4*)(ows + ((size_t)(b * 8 + h) * S_ + s0 + row) * 64 + li * 8) = vv;
    }
}

// ---------------------------------------------------------------------------
// Kernel 1b: V projection, pre-transposed output v_ws: [BH][64][S] bf16.
// 64 s-rows x 512 c per block; V^T tile staged in 64KB LDS, coalesced out.
// grid: (B*S/64), block 256 (wave w: sub-tile w>>1, s-half w&1).
// ---------------------------------------------------------------------------
__global__ __launch_bounds__(256)
void proj_v_kernel(const float* __restrict__ value,
                   const float* __restrict__ Wv, const float* __restrict__ bv,
                   short* __restrict__ vws)
{
    __shared__ __align__(16) short vtile[2 * 512 * 32];   // 64 KB exactly

    const int tid  = threadIdx.x;
    const int wave = tid >> 6;
    const int lane = tid & 63;
    const int n    = lane & 15;
    const int quad = lane >> 4;
    const int r0   = blockIdx.x * 64;
    const int b    = r0 >> 11;
    const int s0   = r0 & 2047;
    const int sub  = wave >> 1;        // 32-s sub-tile
    const int sh   = (wave & 1) * 16;  // 16-s half within sub-tile

    // B-frag: value rows
    bf16x8 bfr = load8_f32_bf16(value + (r0 + sub * 32 + sh + n) * 32 + quad * 8);
    #pragma unroll
    for (int i = 0; i < 32; ++i) {
        const int c0 = i * 16;
        bf16x8 af = load8_f32_bf16(Wv + (c0 + n) * 32 + quad * 8);
        f32x4 acc = {0.f, 0.f, 0.f, 0.f};
        acc = __builtin_amdgcn_mfma_f32_16x16x32_bf16(af, bfr, acc, 0, 0, 0);
        #pragma unroll
        for (int r = 0; r < 4; ++r) {
            const int dc = c0 + quad * 4 + r;    // proj col (row of V^T)
            float v = acc[r] + bv[dc];
            vtile[(sub * 512 + dc) * 32 + sh + n] = f2bf(v);  // col = n -> s-local
        }
    }
    __syncthreads();

    // write out: 1024 chunks (sub,c) of 64B (4 lanes x 16B), coalesced
    #pragma unroll
    for (int k = 0; k < 16; ++k) {
        const int slot = k * 256 + tid;
        const int li   = slot & 3;
        const int c    = (slot >> 2) & 511;
        const int sb   = slot >> 11;
        uint4 vv = *(const uint4*)(vtile + (sb * 512 + c) * 32 + li * 8);
        *(uint4*)(vws + ((size_t)(b * 8 + (c >> 6)) * 64 + (c & 63)) * S_
                      + s0 + sb * 32 + li * 8) = vv;
    }
}

// ---------------------------------------------------------------------------
// Kernel 2: flash attention, max-free softmax (scores bounded: |s|<~8 << 127).
// Block = 256 thr = 4 waves; each wave owns 32 q-rows (2 strips of 16) ->
// grid.x=16 -> 1024 blocks = 4 blocks/CU (was 2: latency-bound at occ 20%).
// K double-buffered in regs; V loaded at iter top (used after QK+exp2).
// LDS only for P C-layout->A-layout round trip, per-wave private.
// grid: (S/128, BH). Output FLOAT32.
// ---------------------------------------------------------------------------
#define PST 56   // P lds row stride (elems): 112B = 16B-aligned, conflict-light

__global__ __launch_bounds__(256, 4)
void flash_kernel(const short* __restrict__ qws, const short* __restrict__ kws,
                  const short* __restrict__ vws, float* __restrict__ out)
{
    __shared__ __align__(16) short plds[4 * 2 * 16 * PST];  // 14.3 KB

    const int tid  = threadIdx.x;
    const int wave = tid >> 6;
    const int lane = tid & 63;
    const int n    = lane & 15;
    const int quad = lane >> 4;
    const int bh   = blockIdx.y;
    const int q0   = blockIdx.x * 128 + wave * 32;

    const short* qbase = qws + (size_t)bh * S_ * D_;
    const short* kbase = kws + (size_t)bh * S_ * D_;
    const short* vbase = vws + (size_t)bh * D_ * S_;

    // Q frags (held whole kernel): strip s, k-half kh
    bf16x8 qf[2][2];
    #pragma unroll
    for (int s = 0; s < 2; ++s)
        #pragma unroll
        for (int kh = 0; kh < 2; ++kh)
            qf[s][kh] = *(const bf16x8*)(qbase + (q0 + s * 16 + n) * D_ + kh * 32 + quad * 8);

    f32x4 o[2][4];        // [strip][d-group] accumulators (C-layout)
    float pl[2][4];       // per-lane partial row sums [strip][reg]
    #pragma unroll
    for (int s = 0; s < 2; ++s) {
        #pragma unroll
        for (int g = 0; g < 4; ++g) o[s][g] = (f32x4){0.f, 0.f, 0.f, 0.f};
        #pragma unroll
        for (int r = 0; r < 4; ++r) pl[s][r] = 0.f;
    }

    short* pb = plds + wave * (2 * 16 * PST);

    // prefetch K tile 0
    bf16x8 kf[2][2];
    #pragma unroll
    for (int h2 = 0; h2 < 2; ++h2)
        #pragma unroll
        for (int kh = 0; kh < 2; ++kh)
            kf[h2][kh] = *(const bf16x8*)(kbase + (h2 * 16 + n) * D_ + kh * 32 + quad * 8);

    for (int it = 0; it < 64; ++it) {
        const int ck = it << 5;
        const int nk = ((it + 1) & 63) << 5;   // wraps to 0: harmless re-read
        // V for current iter (first used after strip0 QK + exp2)
        bf16x8 vf[4];
        #pragma unroll
        for (int g = 0; g < 4; ++g)
            vf[g] = *(const bf16x8*)(vbase + (g * 16 + n) * S_ + ck + quad * 8);
        // K prefetch for next iter
        bf16x8 nkf[2][2];
        #pragma unroll
        for (int h2 = 0; h2 < 2; ++h2)
            #pragma unroll
            for (int kh = 0; kh < 2; ++kh)
                nkf[h2][kh] = *(const bf16x8*)(kbase + (nk + h2 * 16 + n) * D_ + kh * 32 + quad * 8);

        // software-pipeline strips: write P(s), consume P(s-1)
        #pragma unroll
        for (int s = 0; s < 3; ++s) {
            if (s < 2) {
                f32x4 sc0 = {0.f, 0.f, 0.f, 0.f}, sc1 = {0.f, 0.f, 0.f, 0.f};
                sc0 = __builtin_amdgcn_mfma_f32_16x16x32_bf16(qf[s][0], kf[0][0], sc0, 0, 0, 0);
                sc0 = __builtin_amdgcn_mfma_f32_16x16x32_bf16(qf[s][1], kf[0][1], sc0, 0, 0, 0);
                sc1 = __builtin_amdgcn_mfma_f32_16x16x32_bf16(qf[s][0], kf[1][0], sc1, 0, 0, 0);
                sc1 = __builtin_amdgcn_mfma_f32_16x16x32_bf16(qf[s][1], kf[1][1], sc1, 0, 0, 0);
                short* pbs = pb + s * (16 * PST);
                #pragma unroll
                for (int r = 0; r < 4; ++r) {
                    float p0 = exp2f(sc0[r]);   // scores pre-scaled by 0.1125*log2e
                    float p1 = exp2f(sc1[r]);
                    pl[s][r] += p0 + p1;
                    const int row = quad * 4 + r;
                    pbs[row * PST + n]      = f2bf(p0);
                    pbs[row * PST + 16 + n] = f2bf(p1);
                }
            }
            if (s > 0) {
                const int sp = s - 1;
                bf16x8 pf = *(const bf16x8*)(pb + sp * (16 * PST) + n * PST + quad * 8);
                #pragma unroll
                for (int g = 0; g < 4; ++g)
                    o[sp][g] = __builtin_amdgcn_mfma_f32_16x16x32_bf16(pf, vf[g], o[sp][g], 0, 0, 0);
            }
        }
        #pragma unroll
        for (int h2 = 0; h2 < 2; ++h2)
            #pragma unroll
            for (int kh = 0; kh < 2; ++kh) kf[h2][kh] = nkf[h2][kh];
    }

    // epilogue: reduce row sums over the 16 col-lanes, normalize, store f32
    const int b = bh >> 3, h = bh & 7;
    #pragma unroll
    for (int s = 0; s < 2; ++s) {
        float rl[4];
        #pragma unroll
        for (int r = 0; r < 4; ++r) {
            float v = pl[s][r];
            v += __shfl_xor(v, 1);
            v += __shfl_xor(v, 2);
            v += __shfl_xor(v, 4);
            v += __shfl_xor(v, 8);
            rl[r] = 1.0f / v;
        }
        #pragma unroll
        for (int g = 0; g < 4; ++g) {
            #pragma unroll
            for (int r = 0; r < 4; ++r) {
                const int sq = q0 + s * 16 + quad * 4 + r;
                const int d  = g * 16 + n;
                out[((size_t)(b * S_ + sq)) * DPROJ_ + h * 64 + d] = o[s][g][r] * rl[r];
            }
        }
    }
}

// ---------------------------------------------------------------------------
extern "C" void kernel_launch(void* const* d_in, const int* in_sizes, int n_in,
                              void* d_out, int out_size, void* d_ws, size_t ws_size,
                              hipStream_t stream)
{
    const float* query = (const float*)d_in[0];
    const float* key   = (const float*)d_in[1];
    const float* value = (const float*)d_in[2];
    // d_in[3] = mask (int32) -- only its shape feeds the reference; unused.
    const float* Wq = (const float*)d_in[4];
    const float* bq = (const float*)d_in[5];
    const float* Wk = (const float*)d_in[6];
    const float* bk = (const float*)d_in[7];
    const float* Wv = (const float*)d_in[8];
    const float* bv = (const float*)d_in[9];

    float* out = (float*)d_out;
    short* ws  = (short*)d_ws;
    const size_t TSZ = (size_t)BH_ * S_ * D_;   // 8.4M bf16 elems per tensor
    short* qws = ws;
    short* kws = ws + TSZ;
    short* vws = ws + 2 * TSZ;

    proj_qk_kernel<<<dim3((B_ * S_) / 16, 2), 256, 0, stream>>>(
        query, key, Wq, bq, Wk, bk, qws, kws);
    proj_v_kernel<<<dim3((B_ * S_) / 64), 256, 0, stream>>>(
        value, Wv, bv, vws);
    flash_kernel<<<dim3(S_ / 128, BH_), 256, 0, stream>>>(qws, kws, vws, out);
}

// Round 5
// 242.911 us; speedup vs baseline: 1.4238x; 1.4238x over previous
//
#include <hip/hip_runtime.h>
#include <hip/hip_bf16.h>
#include <math.h>

// Problem constants
#define B_   8
#define H_   8
#define S_   2048
#define D_   64      // head dim
#define BH_  64      // B*H
#define DPROJ_ 512

typedef __attribute__((ext_vector_type(8))) _Float16 f16x8;
typedef __attribute__((ext_vector_type(4))) float f32x4;

static __device__ __forceinline__ short f16bits(float f) {
    return __builtin_bit_cast(short, (_Float16)f);   // v_cvt_f16_f32 (RNE), 1 instr
}

// load 8 consecutive f32 and convert to an f16x8 fragment
static __device__ __forceinline__ f16x8 load8_f32_f16(const float* p) {
    const float4 a = ((const float4*)p)[0];
    const float4 b = ((const float4*)p)[1];
    f16x8 r;
    r[0] = (_Float16)a.x; r[1] = (_Float16)a.y; r[2] = (_Float16)a.z; r[3] = (_Float16)a.w;
    r[4] = (_Float16)b.x; r[5] = (_Float16)b.y; r[6] = (_Float16)b.z; r[7] = (_Float16)b.w;
    return r;
}

// ---------------------------------------------------------------------------
// Kernel 1a: Q/K projection. 16 rows x 512 cols per block; C-tiles staged in
// LDS, then written out as coalesced dwordx4.
//   q_ws,k_ws: [BH][S][64] f16. q pre-scaled by 0.1125 (=0.9/8).
// grid: (B*S/16, 2), block 256.
// ---------------------------------------------------------------------------
#define QKST 520   // LDS row stride (shorts): 1040B, 16B-aligned rows

__global__ __launch_bounds__(256)
void proj_qk_kernel(const float* __restrict__ query, const float* __restrict__ key,
                    const float* __restrict__ Wq, const float* __restrict__ bq,
                    const float* __restrict__ Wk, const float* __restrict__ bk,
                    short* __restrict__ qws, short* __restrict__ kws)
{
    __shared__ __align__(16) short tile[16 * QKST];

    const int tid  = threadIdx.x;
    const int wave = tid >> 6;
    const int lane = tid & 63;
    const int n    = lane & 15;
    const int quad = lane >> 4;
    const int r0   = blockIdx.x * 16;
    const int kind = blockIdx.y;             // 0=q, 1=k
    const int b    = r0 >> 11;
    const int s0   = r0 & 2047;
    const float QS = 0.1125f;                // (1-dropout)/num_heads = 0.9/8

    const float* X    = kind ? key : query;
    const float* W    = kind ? Wk  : Wq;
    const float* bias = kind ? bk  : bq;
    short*       ows  = kind ? kws : qws;

    // A-frag: input rows (m = n), k = quad*8 + j
    f16x8 af = load8_f32_f16(X + (r0 + n) * 32 + quad * 8);
    #pragma unroll
    for (int i = 0; i < 8; ++i) {
        const int c0 = wave * 128 + i * 16;
        f16x8 bfr = load8_f32_f16(W + (c0 + n) * 32 + quad * 8);
        f32x4 acc = {0.f, 0.f, 0.f, 0.f};
        acc = __builtin_amdgcn_mfma_f32_16x16x32_f16(af, bfr, acc, 0, 0, 0);
        const int c = c0 + n;                // C/D col = lane&15
        const float bsf = bias[c];
        #pragma unroll
        for (int r = 0; r < 4; ++r) {
            float v = acc[r] + bsf;
            if (kind == 0) v *= QS;
            tile[(quad * 4 + r) * QKST + c] = f16bits(v);   // row = quad*4+r
        }
    }
    __syncthreads();

    // write out: 128 chunks of (h,row), each 128B (8 lanes x 16B), coalesced
    #pragma unroll
    for (int k = 0; k < 4; ++k) {
        const int slot = k * 256 + tid;
        const int li   = slot & 7;
        const int chunk= slot >> 3;
        const int row  = chunk & 15;
        const int h    = chunk >> 4;
        uint4 vv = *(const uint4*)(tile + row * QKST + h * 64 + li * 8);
        *(uint4*)(ows + ((size_t)(b * 8 + h) * S_ + s0 + row) * 64 + li * 8) = vv;
    }
}

// ---------------------------------------------------------------------------
// Kernel 1b: V projection, pre-transposed output v_ws: [BH][64][S] f16.
// 64 s-rows x 256 c per block (c-split for 2x blocks); 32KB LDS stage.
// grid: (B*S/64, 2), block 256.
// ---------------------------------------------------------------------------
__global__ __launch_bounds__(256)
void proj_v_kernel(const float* __restrict__ value,
                   const float* __restrict__ Wv, const float* __restrict__ bv,
                   short* __restrict__ vws)
{
    __shared__ __align__(16) short vtile[2 * 256 * 32];   // 32 KB

    const int tid  = threadIdx.x;
    const int wave = tid >> 6;
    const int lane = tid & 63;
    const int n    = lane & 15;
    const int quad = lane >> 4;
    const int r0   = blockIdx.x * 64;
    const int cb   = blockIdx.y * 256;  // c-range base
    const int b    = r0 >> 11;
    const int s0   = r0 & 2047;
    const int sub  = wave >> 1;        // 32-s sub-tile
    const int sh   = (wave & 1) * 16;  // 16-s half within sub-tile

    // B-frag: value rows
    f16x8 bfr = load8_f32_f16(value + (r0 + sub * 32 + sh + n) * 32 + quad * 8);
    #pragma unroll
    for (int i = 0; i < 16; ++i) {
        const int c0 = cb + i * 16;
        f16x8 af = load8_f32_f16(Wv + (c0 + n) * 32 + quad * 8);
        f32x4 acc = {0.f, 0.f, 0.f, 0.f};
        acc = __builtin_amdgcn_mfma_f32_16x16x32_f16(af, bfr, acc, 0, 0, 0);
        #pragma unroll
        for (int r = 0; r < 4; ++r) {
            const int dc = c0 + quad * 4 + r;    // proj col (row of V^T)
            float v = acc[r] + bv[dc];
            vtile[(sub * 256 + (dc - cb)) * 32 + sh + n] = f16bits(v);
        }
    }
    __syncthreads();

    // write out: 512 chunks (sub,c) of 64B (4 lanes x 16B), coalesced
    #pragma unroll
    for (int k = 0; k < 8; ++k) {
        const int slot = k * 256 + tid;
        const int li   = slot & 3;
        const int cl   = (slot >> 2) & 255;
        const int sb   = slot >> 10;
        const int c    = cb + cl;
        uint4 vv = *(const uint4*)(vtile + (sb * 256 + cl) * 32 + li * 8);
        *(uint4*)(vws + ((size_t)(b * 8 + (c >> 6)) * 64 + (c & 63)) * S_
                      + s0 + sb * 32 + li * 8) = vv;
    }
}

// ---------------------------------------------------------------------------
// Kernel 2: flash attention, max-free softmax (scores bounded: |s|<~8).
// R3 memory shape: 4 waves x 64 q-rows, K AND V prefetched a full iteration
// ahead. Softmax scalar path rebuilt: __expf (native v_exp_f32) + single
// v_cvt_f16_f32 stores (was libm exp2f + 4-op bf16 emulation = VALU-bound).
// grid: (S/256, BH). Output FLOAT32.
// ---------------------------------------------------------------------------
#define PST 56   // P lds row stride (elems): 112B, 16B-aligned, 2-way max (free)

__global__ __launch_bounds__(256, 2)
void flash_kernel(const short* __restrict__ qws, const short* __restrict__ kws,
                  const short* __restrict__ vws, float* __restrict__ out)
{
    __shared__ __align__(16) short plds[4 * 4 * 16 * PST];  // [wave][strip][16][PST]

    const int tid  = threadIdx.x;
    const int wave = tid >> 6;
    const int lane = tid & 63;
    const int n    = lane & 15;
    const int quad = lane >> 4;
    const int bh   = blockIdx.y;
    const int q0   = blockIdx.x * 256 + wave * 64;

    const short* qbase = qws + (size_t)bh * S_ * D_;
    const short* kbase = kws + (size_t)bh * S_ * D_;
    const short* vbase = vws + (size_t)bh * D_ * S_;

    // Q frags (held whole kernel): strip s, k-half kh
    f16x8 qf[4][2];
    #pragma unroll
    for (int s = 0; s < 4; ++s)
        #pragma unroll
        for (int kh = 0; kh < 2; ++kh)
            qf[s][kh] = *(const f16x8*)(qbase + (q0 + s * 16 + n) * D_ + kh * 32 + quad * 8);

    f32x4 o[4][4];        // [strip][d-group] accumulators (C-layout)
    float pl[4][4];       // per-lane partial row sums [strip][reg]
    #pragma unroll
    for (int s = 0; s < 4; ++s) {
        #pragma unroll
        for (int g = 0; g < 4; ++g) o[s][g] = (f32x4){0.f, 0.f, 0.f, 0.f};
        #pragma unroll
        for (int r = 0; r < 4; ++r) pl[s][r] = 0.f;
    }

    short* pb = plds + wave * (4 * 16 * PST);

    // prefetch K/V tile 0
    f16x8 kf[2][2], vf[4];
    #pragma unroll
    for (int h2 = 0; h2 < 2; ++h2)
        #pragma unroll
        for (int kh = 0; kh < 2; ++kh)
            kf[h2][kh] = *(const f16x8*)(kbase + (h2 * 16 + n) * D_ + kh * 32 + quad * 8);
    #pragma unroll
    for (int g = 0; g < 4; ++g)
        vf[g] = *(const f16x8*)(vbase + (g * 16 + n) * S_ + quad * 8);

    #pragma unroll 2
    for (int it = 0; it < 64; ++it) {
        const int nk = ((it + 1) & 63) << 5;   // next k0 (wraps to 0: harmless re-read)
        f16x8 nkf[2][2], nvf[4];
        #pragma unroll
        for (int h2 = 0; h2 < 2; ++h2)
            #pragma unroll
            for (int kh = 0; kh < 2; ++kh)
                nkf[h2][kh] = *(const f16x8*)(kbase + (nk + h2 * 16 + n) * D_ + kh * 32 + quad * 8);
        #pragma unroll
        for (int g = 0; g < 4; ++g)
            nvf[g] = *(const f16x8*)(vbase + (g * 16 + n) * S_ + nk + quad * 8);

        // software-pipeline strips: write P(s), consume P(s-1)
        #pragma unroll
        for (int s = 0; s < 5; ++s) {
            if (s < 4) {
                f32x4 sc0 = {0.f, 0.f, 0.f, 0.f}, sc1 = {0.f, 0.f, 0.f, 0.f};
                sc0 = __builtin_amdgcn_mfma_f32_16x16x32_f16(qf[s][0], kf[0][0], sc0, 0, 0, 0);
                sc0 = __builtin_amdgcn_mfma_f32_16x16x32_f16(qf[s][1], kf[0][1], sc0, 0, 0, 0);
                sc1 = __builtin_amdgcn_mfma_f32_16x16x32_f16(qf[s][0], kf[1][0], sc1, 0, 0, 0);
                sc1 = __builtin_amdgcn_mfma_f32_16x16x32_f16(qf[s][1], kf[1][1], sc1, 0, 0, 0);
                short* pbs = pb + s * (16 * PST);
                #pragma unroll
                for (int r = 0; r < 4; ++r) {
                    float p0 = __expf(sc0[r]);   // q pre-scaled by 0.1125
                    float p1 = __expf(sc1[r]);
                    pl[s][r] += p0 + p1;
                    const int row = quad * 4 + r;
                    pbs[row * PST + n]      = f16bits(p0);
                    pbs[row * PST + 16 + n] = f16bits(p1);
                }
            }
            if (s > 0) {
                const int sp = s - 1;
                f16x8 pf = *(const f16x8*)(pb + sp * (16 * PST) + n * PST + quad * 8);
                #pragma unroll
                for (int g = 0; g < 4; ++g)
                    o[sp][g] = __builtin_amdgcn_mfma_f32_16x16x32_f16(pf, vf[g], o[sp][g], 0, 0, 0);
            }
        }
        #pragma unroll
        for (int h2 = 0; h2 < 2; ++h2)
            #pragma unroll
            for (int kh = 0; kh < 2; ++kh) kf[h2][kh] = nkf[h2][kh];
        #pragma unroll
        for (int g = 0; g < 4; ++g) vf[g] = nvf[g];
    }

    // epilogue: reduce row sums over the 16 col-lanes, normalize, store f32
    const int b = bh >> 3, h = bh & 7;
    #pragma unroll
    for (int s = 0; s < 4; ++s) {
        float rl[4];
        #pragma unroll
        for (int r = 0; r < 4; ++r) {
            float v = pl[s][r];
            v += __shfl_xor(v, 1);
            v += __shfl_xor(v, 2);
            v += __shfl_xor(v, 4);
            v += __shfl_xor(v, 8);
            rl[r] = 1.0f / v;
        }
        #pragma unroll
        for (int g = 0; g < 4; ++g) {
            #pragma unroll
            for (int r = 0; r < 4; ++r) {
                const int sq = q0 + s * 16 + quad * 4 + r;
                const int d  = g * 16 + n;
                out[((size_t)(b * S_ + sq)) * DPROJ_ + h * 64 + d] = o[s][g][r] * rl[r];
            }
        }
    }
}

// ---------------------------------------------------------------------------
extern "C" void kernel_launch(void* const* d_in, const int* in_sizes, int n_in,
                              void* d_out, int out_size, void* d_ws, size_t ws_size,
                              hipStream_t stream)
{
    const float* query = (const float*)d_in[0];
    const float* key   = (const float*)d_in[1];
    const float* value = (const float*)d_in[2];
    // d_in[3] = mask (int32) -- only its shape feeds the reference; unused.
    const float* Wq = (const float*)d_in[4];
    const float* bq = (const float*)d_in[5];
    const float* Wk = (const float*)d_in[6];
    const float* bk = (const float*)d_in[7];
    const float* Wv = (const float*)d_in[8];
    const float* bv = (const float*)d_in[9];

    float* out = (float*)d_out;
    short* ws  = (short*)d_ws;
    const size_t TSZ = (size_t)BH_ * S_ * D_;   // 8.4M f16 elems per tensor
    short* qws = ws;
    short* kws = ws + TSZ;
    short* vws = ws + 2 * TSZ;

    proj_qk_kernel<<<dim3((B_ * S_) / 16, 2), 256, 0, stream>>>(
        query, key, Wq, bq, Wk, bk, qws, kws);
    proj_v_kernel<<<dim3((B_ * S_) / 64, 2), 256, 0, stream>>>(
        value, Wv, bv, vws);
    flash_kernel<<<dim3(S_ / 256, BH_), 256, 0, stream>>>(qws, kws, vws, out);
}

// Round 6
// 231.928 us; speedup vs baseline: 1.4913x; 1.0474x over previous
//
#include <hip/hip_runtime.h>
#include <hip/hip_bf16.h>
#include <math.h>

// Problem constants
#define B_   8
#define H_   8
#define S_   2048
#define D_   64      // head dim
#define BH_  64      // B*H
#define DPROJ_ 512

typedef __attribute__((ext_vector_type(8)))  _Float16 f16x8;
typedef __attribute__((ext_vector_type(4)))  float    f32x4;
typedef __attribute__((ext_vector_type(16))) float    f32x16;
typedef __attribute__((ext_vector_type(4)))  int      i32x4;

static __device__ __forceinline__ short f16bits(float f) {
    return __builtin_bit_cast(short, (_Float16)f);   // v_cvt_f16_f32 (RNE)
}

// load 8 consecutive f32 and convert to an f16x8 fragment
static __device__ __forceinline__ f16x8 load8_f32_f16(const float* p) {
    const float4 a = ((const float4*)p)[0];
    const float4 b = ((const float4*)p)[1];
    f16x8 r;
    r[0] = (_Float16)a.x; r[1] = (_Float16)a.y; r[2] = (_Float16)a.z; r[3] = (_Float16)a.w;
    r[4] = (_Float16)b.x; r[5] = (_Float16)b.y; r[6] = (_Float16)b.z; r[7] = (_Float16)b.w;
    return r;
}

// ---------------------------------------------------------------------------
// Kernel 1a: Q/K projection (unchanged from R5 — passes, cost minor).
//   q_ws,k_ws: [BH][S][64] f16. q pre-scaled by 0.1125 (=0.9/8).
// ---------------------------------------------------------------------------
#define QKST 520

__global__ __launch_bounds__(256)
void proj_qk_kernel(const float* __restrict__ query, const float* __restrict__ key,
                    const float* __restrict__ Wq, const float* __restrict__ bq,
                    const float* __restrict__ Wk, const float* __restrict__ bk,
                    short* __restrict__ qws, short* __restrict__ kws)
{
    __shared__ __align__(16) short tile[16 * QKST];

    const int tid  = threadIdx.x;
    const int wave = tid >> 6;
    const int lane = tid & 63;
    const int n    = lane & 15;
    const int quad = lane >> 4;
    const int r0   = blockIdx.x * 16;
    const int kind = blockIdx.y;             // 0=q, 1=k
    const int b    = r0 >> 11;
    const int s0   = r0 & 2047;
    const float QS = 0.1125f;                // (1-dropout)/num_heads = 0.9/8

    const float* X    = kind ? key : query;
    const float* W    = kind ? Wk  : Wq;
    const float* bias = kind ? bk  : bq;
    short*       ows  = kind ? kws : qws;

    f16x8 af = load8_f32_f16(X + (r0 + n) * 32 + quad * 8);
    #pragma unroll
    for (int i = 0; i < 8; ++i) {
        const int c0 = wave * 128 + i * 16;
        f16x8 bfr = load8_f32_f16(W + (c0 + n) * 32 + quad * 8);
        f32x4 acc = {0.f, 0.f, 0.f, 0.f};
        acc = __builtin_amdgcn_mfma_f32_16x16x32_f16(af, bfr, acc, 0, 0, 0);
        const int c = c0 + n;
        const float bsf = bias[c];
        #pragma unroll
        for (int r = 0; r < 4; ++r) {
            float v = acc[r] + bsf;
            if (kind == 0) v *= QS;
            tile[(quad * 4 + r) * QKST + c] = f16bits(v);
        }
    }
    __syncthreads();

    #pragma unroll
    for (int k = 0; k < 4; ++k) {
        const int slot = k * 256 + tid;
        const int li   = slot & 7;
        const int chunk= slot >> 3;
        const int row  = chunk & 15;
        const int h    = chunk >> 4;
        uint4 vv = *(const uint4*)(tile + row * QKST + h * 64 + li * 8);
        *(uint4*)(ows + ((size_t)(b * 8 + h) * S_ + s0 + row) * 64 + li * 8) = vv;
    }
}

// ---------------------------------------------------------------------------
// Kernel 1b: V projection (unchanged from R5). v_ws: [BH][64][S] f16.
// ---------------------------------------------------------------------------
__global__ __launch_bounds__(256)
void proj_v_kernel(const float* __restrict__ value,
                   const float* __restrict__ Wv, const float* __restrict__ bv,
                   short* __restrict__ vws)
{
    __shared__ __align__(16) short vtile[2 * 256 * 32];   // 32 KB

    const int tid  = threadIdx.x;
    const int wave = tid >> 6;
    const int lane = tid & 63;
    const int n    = lane & 15;
    const int quad = lane >> 4;
    const int r0   = blockIdx.x * 64;
    const int cb   = blockIdx.y * 256;
    const int b    = r0 >> 11;
    const int s0   = r0 & 2047;
    const int sub  = wave >> 1;
    const int sh   = (wave & 1) * 16;

    f16x8 bfr = load8_f32_f16(value + (r0 + sub * 32 + sh + n) * 32 + quad * 8);
    #pragma unroll
    for (int i = 0; i < 16; ++i) {
        const int c0 = cb + i * 16;
        f16x8 af = load8_f32_f16(Wv + (c0 + n) * 32 + quad * 8);
        f32x4 acc = {0.f, 0.f, 0.f, 0.f};
        acc = __builtin_amdgcn_mfma_f32_16x16x32_f16(af, bfr, acc, 0, 0, 0);
        #pragma unroll
        for (int r = 0; r < 4; ++r) {
            const int dc = c0 + quad * 4 + r;
            float v = acc[r] + bv[dc];
            vtile[(sub * 256 + (dc - cb)) * 32 + sh + n] = f16bits(v);
        }
    }
    __syncthreads();

    #pragma unroll
    for (int k = 0; k < 8; ++k) {
        const int slot = k * 256 + tid;
        const int li   = slot & 3;
        const int cl   = (slot >> 2) & 255;
        const int sb   = slot >> 10;
        const int c    = cb + cl;
        uint4 vv = *(const uint4*)(vtile + (sb * 256 + cl) * 32 + li * 8);
        *(uint4*)(vws + ((size_t)(b * 8 + (c >> 6)) * 64 + (c & 63)) * S_
                      + s0 + sb * 32 + li * 8) = vv;
    }
}

// ---------------------------------------------------------------------------
// Kernel 2: flash attention, 32x32x16 MFMA, REGISTER-ONLY P transform.
//   S^T = K_tile . Q^T   (A=K rows, B=Q^T)  -> C-layout: q=lane&31, k in regs
//   P^T -> PV B-operand via cvt_pkrtz + shfl_xor(32) + cndmask (no LDS!)
//   O^T = V^T . P^T      (A=V^T rows from pre-transposed vws)
// Wave = 64 q-rows (2 q-groups of 32); 64 k-iters of 32; K/V prefetch 1 iter.
// LDS only for the one-time O^T->O epilogue transpose (per-wave, no barrier).
// grid: (S/256, BH), block 256. Output FLOAT32.
// ---------------------------------------------------------------------------
#define OST 68   // epilogue LDS row stride (f32): 68%32=4 -> spreads banks, 16B-aligned

__global__ __launch_bounds__(256, 2)
void flash_kernel(const short* __restrict__ qws, const short* __restrict__ kws,
                  const short* __restrict__ vws, float* __restrict__ out)
{
    __shared__ __align__(16) float olds[4 * 32 * OST];   // 34.8 KB

    const int tid  = threadIdx.x;
    const int wave = tid >> 6;
    const int lane = tid & 63;
    const int m32  = lane & 31;
    const int lh   = lane >> 5;          // lane-half
    const int koff = lh * 8;
    const bool lh0 = (lh == 0);
    const int bh   = blockIdx.y;
    const int q0   = blockIdx.x * 256 + wave * 64;

    const short* qbase = qws + (size_t)bh * S_ * D_;
    const short* kbase = kws + (size_t)bh * S_ * D_;
    const short* vbase = vws + (size_t)bh * D_ * S_;

    // Q^T B-frags (held): qb[qg][h]: B[d=h*16+lh*8+j][q=m32]
    f16x8 qb[2][4];
    #pragma unroll
    for (int qg = 0; qg < 2; ++qg)
        #pragma unroll
        for (int h = 0; h < 4; ++h)
            qb[qg][h] = *(const f16x8*)(qbase + (q0 + qg * 32 + m32) * D_ + h * 16 + koff);

    f32x16 o[2][2];      // [qg][d-tile] O^T accumulators
    float  pl[2] = {0.f, 0.f};
    #pragma unroll
    for (int qg = 0; qg < 2; ++qg)
        #pragma unroll
        for (int t = 0; t < 2; ++t)
            #pragma unroll
            for (int r = 0; r < 16; ++r) o[qg][t][r] = 0.f;

    // K A-frags / V^T A-frags, double-buffered
    f16x8 kf[2][4], va[2][4];
    #pragma unroll
    for (int h = 0; h < 4; ++h)
        kf[0][h] = *(const f16x8*)(kbase + (size_t)(m32) * D_ + h * 16 + koff);
    #pragma unroll
    for (int t = 0; t < 2; ++t)
        #pragma unroll
        for (int kh = 0; kh < 2; ++kh)
            va[0][t * 2 + kh] = *(const f16x8*)(vbase + (size_t)(t * 32 + m32) * S_ + kh * 16 + koff);

    #pragma unroll 2
    for (int it = 0; it < 64; ++it) {
        const int cur = it & 1, nx = cur ^ 1;
        const int nkt = ((it + 1) & 63) << 5;   // wraps: harmless re-read
        // prefetch next K/V
        #pragma unroll
        for (int h = 0; h < 4; ++h)
            kf[nx][h] = *(const f16x8*)(kbase + (size_t)(nkt + m32) * D_ + h * 16 + koff);
        #pragma unroll
        for (int t = 0; t < 2; ++t)
            #pragma unroll
            for (int kh = 0; kh < 2; ++kh)
                va[nx][t * 2 + kh] = *(const f16x8*)(vbase + (size_t)(t * 32 + m32) * S_ + nkt + kh * 16 + koff);

        #pragma unroll
        for (int qg = 0; qg < 2; ++qg) {
            // S^T[k][q] for this 32k x 32q tile
            f32x16 st;
            #pragma unroll
            for (int r = 0; r < 16; ++r) st[r] = 0.f;
            #pragma unroll
            for (int h = 0; h < 4; ++h)
                st = __builtin_amdgcn_mfma_f32_32x32x16_f16(kf[cur][h], qb[qg][h], st, 0, 0, 0);

            // exp (q pre-scaled by 0.1125); accumulate row sums (per-lane half)
            float p[16];
            #pragma unroll
            for (int r = 0; r < 16; ++r) p[r] = __expf(st[r]);
            float s01 = (p[0]+p[1]) + (p[2]+p[3]);
            float s23 = (p[4]+p[5]) + (p[6]+p[7]);
            float s45 = (p[8]+p[9]) + (p[10]+p[11]);
            float s67 = (p[12]+p[13]) + (p[14]+p[15]);
            pl[qg] += (s01 + s23) + (s45 + s67);

            // pack pairs to f16x2 (RTZ) and build PV B-frags via xor-32 swap
            unsigned int pk[8], xk[8];
            #pragma unroll
            for (int i = 0; i < 8; ++i)
                pk[i] = __builtin_bit_cast(unsigned int,
                          __builtin_amdgcn_cvt_pkrtz(p[2 * i], p[2 * i + 1]));
            #pragma unroll
            for (int i = 0; i < 8; ++i)
                xk[i] = (unsigned int)__shfl_xor((int)pk[i], 32);

            i32x4 bi0, bi1;
            bi0[0] = (int)(lh0 ? pk[0] : xk[2]);
            bi0[1] = (int)(lh0 ? pk[1] : xk[3]);
            bi0[2] = (int)(lh0 ? xk[0] : pk[2]);
            bi0[3] = (int)(lh0 ? xk[1] : pk[3]);
            bi1[0] = (int)(lh0 ? pk[4] : xk[6]);
            bi1[1] = (int)(lh0 ? pk[5] : xk[7]);
            bi1[2] = (int)(lh0 ? xk[4] : pk[6]);
            bi1[3] = (int)(lh0 ? xk[5] : pk[7]);
            f16x8 bf0 = __builtin_bit_cast(f16x8, bi0);
            f16x8 bf1 = __builtin_bit_cast(f16x8, bi1);

            // O^T[d][q] += V^T . P^T   (two d-tiles, two k-halves)
            #pragma unroll
            for (int t = 0; t < 2; ++t) {
                o[qg][t] = __builtin_amdgcn_mfma_f32_32x32x16_f16(va[cur][t * 2 + 0], bf0, o[qg][t], 0, 0, 0);
                o[qg][t] = __builtin_amdgcn_mfma_f32_32x32x16_f16(va[cur][t * 2 + 1], bf1, o[qg][t], 0, 0, 0);
            }
        }
    }

    // epilogue: per qg: complete row sums across lane-halves, normalize,
    // transpose O^T -> O through per-wave LDS, coalesced f32x4 stores.
    const int b = bh >> 3, h = bh & 7;
    float* ow = olds + wave * (32 * OST);
    #pragma unroll
    for (int qg = 0; qg < 2; ++qg) {
        float rs = pl[qg] + __shfl_xor(pl[qg], 32);
        float rl = 1.0f / rs;
        // write: lane holds q=m32, d = t*32 + 8*g + 4*lh + i  (i contiguous)
        #pragma unroll
        for (int t = 0; t < 2; ++t)
            #pragma unroll
            for (int g = 0; g < 4; ++g) {
                f32x4 w;
                w[0] = o[qg][t][g * 4 + 0] * rl;
                w[1] = o[qg][t][g * 4 + 1] * rl;
                w[2] = o[qg][t][g * 4 + 2] * rl;
                w[3] = o[qg][t][g * 4 + 3] * rl;
                *(f32x4*)(ow + m32 * OST + t * 32 + 8 * g + 4 * lh) = w;
            }
        // read rows (q-major) and store coalesced: 4 q-rows x 16 lanes per instr
        #pragma unroll
        for (int c = 0; c < 8; ++c) {
            const int row = c * 4 + (lane >> 4);
            f32x4 v = *(const f32x4*)(ow + row * OST + (lane & 15) * 4);
            const int sq = q0 + qg * 32 + row;
            *(f32x4*)(out + ((size_t)(b * S_ + sq)) * DPROJ_ + h * 64 + (lane & 15) * 4) = v;
        }
    }
}

// ---------------------------------------------------------------------------
extern "C" void kernel_launch(void* const* d_in, const int* in_sizes, int n_in,
                              void* d_out, int out_size, void* d_ws, size_t ws_size,
                              hipStream_t stream)
{
    const float* query = (const float*)d_in[0];
    const float* key   = (const float*)d_in[1];
    const float* value = (const float*)d_in[2];
    // d_in[3] = mask (int32) -- only its shape feeds the reference; unused.
    const float* Wq = (const float*)d_in[4];
    const float* bq = (const float*)d_in[5];
    const float* Wk = (const float*)d_in[6];
    const float* bk = (const float*)d_in[7];
    const float* Wv = (const float*)d_in[8];
    const float* bv = (const float*)d_in[9];

    float* out = (float*)d_out;
    short* ws  = (short*)d_ws;
    const size_t TSZ = (size_t)BH_ * S_ * D_;
    short* qws = ws;
    short* kws = ws + TSZ;
    short* vws = ws + 2 * TSZ;

    proj_qk_kernel<<<dim3((B_ * S_) / 16, 2), 256, 0, stream>>>(
        query, key, Wq, bq, Wk, bk, qws, kws);
    proj_v_kernel<<<dim3((B_ * S_) / 64, 2), 256, 0, stream>>>(
        value, Wv, bv, vws);
    flash_kernel<<<dim3(S_ / 256, BH_), 256, 0, stream>>>(qws, kws, vws, out);
}